// Round 3
// baseline (357.072 us; speedup 1.0000x reference)
//
#include <hip/hip_runtime.h>
#include <hip/hip_bf16.h>
#include <stdint.h>

// AutoInt: B=2048, F=64, D=128, H=8, P=64, V=100000  -- FP32 inputs/outputs.
// One block per batch element. 256 threads = 4 waves.
// Wave w computes projection matrix w (q,k,v^T,r) each head; scores/softmax/av
// work is split across waves by 16-column slabs. Compute path converts to bf16
// for MFMA; all accumulation in fp32.
//
// d_ws (if >= 512 KB) holds W transposed+converted to bf16 in B-fragment-
// friendly layout Wt[mat][col(512)][d(128)]; otherwise a strided-load fallback
// gathers W fragments directly from the fp32 matrices.

typedef __attribute__((ext_vector_type(8))) __bf16 bf16x8;
typedef __attribute__((ext_vector_type(4))) float f32x4;

#define LDP 72   // padded row stride (elements) for [64][64] bf16 LDS arrays

__device__ inline unsigned short f2bf(float f) {
    unsigned u = __float_as_uint(f);
    unsigned r = (u + 0x7fff + ((u >> 16) & 1)) >> 16;
    return (unsigned short)r;
}
__device__ inline float bf2f(unsigned short u) {
    return __uint_as_float(((unsigned)u) << 16);
}

union bfpack { unsigned short u[8]; bf16x8 v; };

// ---- prep: transpose+convert Wq,Wk,Wv,Wr fp32 [128][512] -> bf16 Wt[4][512][128]
__global__ void prep_w(const float* __restrict__ Wq,
                       const float* __restrict__ Wk,
                       const float* __restrict__ Wv,
                       const float* __restrict__ Wr,
                       unsigned short* __restrict__ Wt) {
    __shared__ __align__(16) unsigned short t[64][72];
    int blk = blockIdx.x;            // 64 blocks: mat(4) x dtile(2) x ctile(8)
    int mat = blk >> 4;
    int dt  = (blk >> 3) & 1;
    int ct  = blk & 7;
    const float* W = (mat == 0) ? Wq : (mat == 1) ? Wk : (mat == 2) ? Wv : Wr;
    int tid  = threadIdx.x;
    int col  = tid & 63;
    int row0 = tid >> 6;             // 0..3
    for (int i = 0; i < 16; i++) {
        int row = row0 + i * 4;      // 0..63 (this is a d-row of W)
        t[row][col] = f2bf(W[(size_t)(dt * 64 + row) * 512 + ct * 64 + col]);
    }
    __syncthreads();
    unsigned short* out = Wt + ((size_t)mat * 512 + ct * 64) * 128 + dt * 64;
    for (int i = 0; i < 16; i++) {
        int row = row0 + i * 4;      // output col-row
        out[(size_t)row * 128 + col] = t[col][row];   // Wt[mat][col][d] = W[d][col]
    }
}

template <int USE_WT>
__global__ __launch_bounds__(256) void autoint_kernel(
        const int* __restrict__ fidx,
        const float* __restrict__ emb,             // [100000][128]
        const float* __restrict__ W0,              // Wq [128][512]
        const float* __restrict__ W1,              // Wk
        const float* __restrict__ W2,              // Wv
        const float* __restrict__ W3,              // Wr
        const unsigned short* __restrict__ Wt,     // bf16 [4][512][128] (fast path)
        const float* __restrict__ out_w,           // [32768]
        const float* __restrict__ out_b,           // [1]
        float* __restrict__ y) {                   // [2048]
    __shared__ __align__(16) unsigned short e_frag[64 * 128];  // A-frag-ordered e (bf16)
    __shared__ __align__(16) unsigned short q_lds[64 * LDP];   // q[f][p]
    __shared__ __align__(16) unsigned short k_lds[64 * LDP];   // k[f][p]
    __shared__ __align__(16) unsigned short vT_lds[64 * LDP];  // v^T[p][f]
    __shared__ __align__(16) unsigned short r_lds[64 * LDP];   // r[f][p]
    __shared__ __align__(16) unsigned short att_lds[64 * LDP]; // att[f_q][f_k]
    __shared__ float red[4];

    const int b    = blockIdx.x;
    const int tid  = threadIdx.x;
    const int wave = tid >> 6;
    const int lane = tid & 63;
    const int quad = lane >> 4;
    const int ln16 = lane & 15;

    const int* idx = fidx + b * 64;

    // ---- gather e (fp32) into bf16 A-fragment order ----
    // slot s: tm=s>>8, ks=(s>>6)&3, quad=(s>>4)&3, m=s&15
    // holds e[f=tm*16+m][d = ks*32 + quad*8 + 0..7]
    for (int it = 0; it < 4; it++) {
        int s  = tid + it * 256;
        int tm = s >> 8, ks = (s >> 6) & 3, qd = (s >> 4) & 3, m = s & 15;
        int f  = tm * 16 + m;
        const float* src = emb + (size_t)idx[f] * 128 + ks * 32 + qd * 8;
        float4 lo = *(const float4*)src;
        float4 hi = *(const float4*)(src + 4);
        ushort4 pa, pb;
        pa.x = f2bf(lo.x); pa.y = f2bf(lo.y); pa.z = f2bf(lo.z); pa.w = f2bf(lo.w);
        pb.x = f2bf(hi.x); pb.y = f2bf(hi.y); pb.z = f2bf(hi.z); pb.w = f2bf(hi.w);
        *(ushort4*)&e_frag[s * 8]     = pa;
        *(ushort4*)&e_frag[s * 8 + 4] = pb;
    }
    __syncthreads();

    float acc_out = 0.f;

    for (int h = 0; h < 8; h++) {
        // ---- projections: wave w computes matrix w slice [64 x 64] ----
        {
            const float* Wsel = (wave == 0) ? W0 : (wave == 1) ? W1
                               : (wave == 2) ? W2 : W3;
            const unsigned short* WtM = Wt + ((size_t)wave * 512 + h * 64) * 128;
            unsigned short* dst = (wave == 0) ? q_lds : (wave == 1) ? k_lds
                                 : (wave == 2) ? vT_lds : r_lds;
            bf16x8 a[4][4];
            for (int tm = 0; tm < 4; tm++)
                for (int ks = 0; ks < 4; ks++)
                    a[tm][ks] = *(const bf16x8*)&e_frag[((tm * 4 + ks) * 64 + lane) * 8];
            for (int tn = 0; tn < 4; tn++) {
                bf16x8 bf[4];
                if (USE_WT) {
                    for (int ks = 0; ks < 4; ks++)
                        bf[ks] = *(const bf16x8*)&WtM[(size_t)(tn * 16 + ln16) * 128 + ks * 32 + quad * 8];
                } else {
                    for (int ks = 0; ks < 4; ks++) {
                        bfpack p;
                        const float* base =
                            Wsel + (size_t)(ks * 32 + quad * 8) * 512 + h * 64 + tn * 16 + ln16;
                        for (int j = 0; j < 8; j++) p.u[j] = f2bf(base[(size_t)j * 512]);
                        bf[ks] = p.v;
                    }
                }
                for (int tm = 0; tm < 4; tm++) {
                    f32x4 acc = {0.f, 0.f, 0.f, 0.f};
                    for (int ks = 0; ks < 4; ks++)
                        acc = __builtin_amdgcn_mfma_f32_16x16x32_bf16(a[tm][ks], bf[ks], acc, 0, 0, 0);
                    if (wave == 2) {
                        // v^T[p = tn*16+ln16][f = tm*16+quad*4 + r]
                        ushort4 pk;
                        pk.x = f2bf(acc[0]); pk.y = f2bf(acc[1]);
                        pk.z = f2bf(acc[2]); pk.w = f2bf(acc[3]);
                        *(ushort4*)&vT_lds[(tn * 16 + ln16) * LDP + tm * 16 + quad * 4] = pk;
                    } else {
                        for (int r = 0; r < 4; r++)
                            dst[(tm * 16 + quad * 4 + r) * LDP + tn * 16 + ln16] = f2bf(acc[r]);
                    }
                }
            }
        }
        __syncthreads();

        // ---- scores = q @ k^T, softmax over q (column-wise), store att ----
        {
            float sc[4][4];  // [tm][r]; this wave owns columns f_k = wave*16 + ln16
            for (int tm = 0; tm < 4; tm++) {
                f32x4 acc = {0.f, 0.f, 0.f, 0.f};
                for (int ks = 0; ks < 2; ks++) {
                    bf16x8 af = *(const bf16x8*)&q_lds[(tm * 16 + ln16) * LDP + ks * 32 + quad * 8];
                    bf16x8 bb = *(const bf16x8*)&k_lds[(wave * 16 + ln16) * LDP + ks * 32 + quad * 8];
                    acc = __builtin_amdgcn_mfma_f32_16x16x32_bf16(af, bb, acc, 0, 0, 0);
                }
                for (int r = 0; r < 4; r++) sc[tm][r] = acc[r];
            }
            // softmax over the q axis = per-column. Each lane holds 16 rows of
            // its column; lanes differing in quad (xor 16, 32) complete it.
            float mx = sc[0][0];
            for (int tm = 0; tm < 4; tm++)
                for (int r = 0; r < 4; r++) mx = fmaxf(mx, sc[tm][r]);
            mx = fmaxf(mx, __shfl_xor(mx, 16));
            mx = fmaxf(mx, __shfl_xor(mx, 32));
            float sum = 0.f;
            for (int tm = 0; tm < 4; tm++)
                for (int r = 0; r < 4; r++) {
                    sc[tm][r] = __expf(sc[tm][r] - mx);
                    sum += sc[tm][r];
                }
            sum += __shfl_xor(sum, 16);
            sum += __shfl_xor(sum, 32);
            float inv = 1.f / sum;
            for (int tm = 0; tm < 4; tm++)
                for (int r = 0; r < 4; r++)
                    att_lds[(tm * 16 + quad * 4 + r) * LDP + wave * 16 + ln16] =
                        f2bf(sc[tm][r] * inv);
        }
        __syncthreads();

        // ---- av = att @ v, combine with r, relu, dot out_w (fp32) ----
        {
            const float* ow = out_w + h * 64 + wave * 16;
            for (int tm = 0; tm < 4; tm++) {
                f32x4 acc = {0.f, 0.f, 0.f, 0.f};
                for (int ks = 0; ks < 2; ks++) {
                    bf16x8 af = *(const bf16x8*)&att_lds[(tm * 16 + ln16) * LDP + ks * 32 + quad * 8];
                    bf16x8 bb = *(const bf16x8*)&vT_lds[(wave * 16 + ln16) * LDP + ks * 32 + quad * 8];
                    acc = __builtin_amdgcn_mfma_f32_16x16x32_bf16(af, bb, acc, 0, 0, 0);
                }
                for (int r = 0; r < 4; r++) {
                    int f = tm * 16 + quad * 4 + r;
                    float mval = acc[r] + bf2f(r_lds[f * LDP + wave * 16 + ln16]);
                    if (mval > 0.f) {
                        acc_out += mval * ow[(size_t)f * 512 + ln16];
                    }
                }
            }
        }
        __syncthreads();
    }

    // ---- block reduction + sigmoid ----
    for (int off = 32; off >= 1; off >>= 1) acc_out += __shfl_xor(acc_out, off);
    if (lane == 0) red[wave] = acc_out;
    __syncthreads();
    if (tid == 0) {
        float s  = red[0] + red[1] + red[2] + red[3] + out_b[0];
        float yv = 1.f / (1.f + __expf(-s));
        y[b] = yv;
    }
}

extern "C" void kernel_launch(void* const* d_in, const int* in_sizes, int n_in,
                              void* d_out, int out_size, void* d_ws, size_t ws_size,
                              hipStream_t stream) {
    (void)in_sizes; (void)n_in; (void)out_size;
    const int*   fidx = (const int*)d_in[0];
    const float* emb  = (const float*)d_in[1];
    const float* Wq   = (const float*)d_in[2];
    const float* Wk   = (const float*)d_in[3];
    const float* Wv   = (const float*)d_in[4];
    const float* Wr   = (const float*)d_in[5];
    const float* ow   = (const float*)d_in[6];
    const float* ob   = (const float*)d_in[7];
    float*       yy   = (float*)d_out;

    const size_t wt_bytes = (size_t)4 * 512 * 128 * sizeof(unsigned short);  // 512 KB
    if (d_ws != nullptr && ws_size >= wt_bytes) {
        unsigned short* Wt = (unsigned short*)d_ws;
        prep_w<<<64, 256, 0, stream>>>(Wq, Wk, Wv, Wr, Wt);
        autoint_kernel<1><<<2048, 256, 0, stream>>>(fidx, emb, Wq, Wk, Wv, Wr, Wt, ow, ob, yy);
    } else {
        autoint_kernel<0><<<2048, 256, 0, stream>>>(fidx, emb, Wq, Wk, Wv, Wr, nullptr, ow, ob, yy);
    }
}

// Round 4
// 294.658 us; speedup vs baseline: 1.2118x; 1.2118x over previous
//
#include <hip/hip_runtime.h>
#include <hip/hip_bf16.h>
#include <stdint.h>

// AutoInt: B=2048, F=64, D=128, H=8, P=64, V=100000 -- FP32 in/out.
// One block per batch element, 256 threads = 4 waves, 3 blocks/CU (44KB LDS).
// Phase1: wave w computes the p-slice [w*16,w*16+16) of q,k,v,r (r kept in
// registers, v stored transposed). Phase2: scores + column softmax (softmax is
// over the q axis). Phase3: att@v + r + relu + dot(out_w).
// e A-fragments are head-invariant -> hoisted into 64 VGPRs; the e LDS region
// is reused for att after the prologue.

typedef __attribute__((ext_vector_type(8))) __bf16 bf16x8;
typedef __attribute__((ext_vector_type(4))) float f32x4;

#define LDP 72   // padded row stride (elements) for [64][64] bf16 LDS arrays

__device__ inline unsigned short f2bf(float f) {
    unsigned u = __float_as_uint(f);
    unsigned r = (u + 0x7fff + ((u >> 16) & 1)) >> 16;
    return (unsigned short)r;
}

// ---- prep: transpose+convert W fp32 [128][512] -> bf16 Wt[4][512][128] ----
// 256 blocks: mat(4) x dtile(8, 16 rows) x ctile(8, 64 cols)
__global__ __launch_bounds__(256) void prep_w(
        const float* __restrict__ Wq, const float* __restrict__ Wk,
        const float* __restrict__ Wv, const float* __restrict__ Wr,
        unsigned short* __restrict__ Wt) {
    __shared__ __align__(16) unsigned short t[64][20];
    int blk = blockIdx.x;
    int mat = blk >> 6;
    int dt8 = (blk >> 3) & 7;        // 16-row group of d
    int ct  = blk & 7;               // 64-col group
    const float* W = (mat == 0) ? Wq : (mat == 1) ? Wk : (mat == 2) ? Wv : Wr;
    int tid  = threadIdx.x;
    int col  = tid & 63;
    int row0 = tid >> 6;             // 0..3
    for (int i = 0; i < 4; i++) {
        int row = row0 + i * 4;      // 0..15 within d-group
        t[col][row] = f2bf(W[(size_t)(dt8 * 16 + row) * 512 + ct * 64 + col]);
    }
    __syncthreads();
    // thread writes ushort4: col = tid&63, rows seg*4..seg*4+3
    int wc  = tid & 63;
    int seg = tid >> 6;              // 0..3
    ushort4 v;
    v.x = t[wc][seg * 4 + 0]; v.y = t[wc][seg * 4 + 1];
    v.z = t[wc][seg * 4 + 2]; v.w = t[wc][seg * 4 + 3];
    *(ushort4*)&Wt[((size_t)mat * 512 + ct * 64 + wc) * 128 + dt8 * 16 + seg * 4] = v;
}

__global__ __launch_bounds__(256, 3) void autoint_kernel(
        const int* __restrict__ fidx,
        const float* __restrict__ emb,             // [100000][128]
        const unsigned short* __restrict__ Wt,     // bf16 [4][512][128]
        const float* __restrict__ out_w,           // [32768]
        const float* __restrict__ out_b,           // [1]
        float* __restrict__ y) {                   // [2048]
    // escratch: e A-fragments during prologue (16384 sh), att (4608 sh) after.
    __shared__ __align__(16) unsigned short escratch[64 * 128];
    __shared__ __align__(16) unsigned short q_lds[64 * LDP];   // q[f][p]
    __shared__ __align__(16) unsigned short k_lds[64 * LDP];   // k[f][p]
    __shared__ __align__(16) unsigned short vT_lds[64 * LDP];  // v^T[p][f]
    __shared__ float red[4];

    const int b    = blockIdx.x;
    const int tid  = threadIdx.x;
    const int wave = tid >> 6;
    const int lane = tid & 63;
    const int quad = lane >> 4;
    const int ln16 = lane & 15;

    const int* idx = fidx + b * 64;

    // ---- gather e (fp32) into bf16 A-fragment order in escratch ----
    // slot s: tm=s>>8, ks=(s>>6)&3, quad=(s>>4)&3, m=s&15
    // holds e[f=tm*16+m][d = ks*32 + quad*8 + 0..7]
    for (int it = 0; it < 4; it++) {
        int s  = tid + it * 256;
        int tm = s >> 8, ks = (s >> 6) & 3, qd = (s >> 4) & 3, m = s & 15;
        int f  = tm * 16 + m;
        const float* src = emb + (size_t)idx[f] * 128 + ks * 32 + qd * 8;
        float4 lo = *(const float4*)src;
        float4 hi = *(const float4*)(src + 4);
        ushort4 pa, pb;
        pa.x = f2bf(lo.x); pa.y = f2bf(lo.y); pa.z = f2bf(lo.z); pa.w = f2bf(lo.w);
        pb.x = f2bf(hi.x); pb.y = f2bf(hi.y); pb.z = f2bf(hi.z); pb.w = f2bf(hi.w);
        *(ushort4*)&escratch[s * 8]     = pa;
        *(ushort4*)&escratch[s * 8 + 4] = pb;
    }
    __syncthreads();

    // ---- hoist e A-fragments into registers (head-invariant) ----
    bf16x8 a[4][4];
    for (int tm = 0; tm < 4; tm++)
        for (int ks = 0; ks < 4; ks++)
            a[tm][ks] = *(const bf16x8*)&escratch[((tm * 4 + ks) * 64 + lane) * 8];
    // escratch region is reused for att from phase2 of head 0 onward; the
    // phase1-end barrier of head 0 orders all A-reads before any att write.
    unsigned short* att_lds = escratch;

    float acc_out = 0.f;
    f32x4 r_reg[4];  // r[f=tm*16+quad*4+r][p=wave*16+ln16] - matches phase3 acc layout

    for (int h = 0; h < 8; h++) {
        // ---- phase1: this wave computes p-slice [wave*16, wave*16+16) of
        //      q, k, v (stored transposed), r (kept in registers) ----
        for (int m = 0; m < 4; m++) {
            const unsigned short* WtM =
                Wt + ((size_t)m * 512 + h * 64 + wave * 16 + ln16) * 128;
            bf16x8 bf[4];
            for (int ks = 0; ks < 4; ks++)
                bf[ks] = *(const bf16x8*)&WtM[ks * 32 + quad * 8];
            for (int tm = 0; tm < 4; tm++) {
                f32x4 acc = {0.f, 0.f, 0.f, 0.f};
                for (int ks = 0; ks < 4; ks++)
                    acc = __builtin_amdgcn_mfma_f32_16x16x32_bf16(a[tm][ks], bf[ks], acc, 0, 0, 0);
                if (m == 0) {
                    for (int r = 0; r < 4; r++)
                        q_lds[(tm * 16 + quad * 4 + r) * LDP + wave * 16 + ln16] = f2bf(acc[r]);
                } else if (m == 1) {
                    for (int r = 0; r < 4; r++)
                        k_lds[(tm * 16 + quad * 4 + r) * LDP + wave * 16 + ln16] = f2bf(acc[r]);
                } else if (m == 2) {
                    ushort4 pk;
                    pk.x = f2bf(acc[0]); pk.y = f2bf(acc[1]);
                    pk.z = f2bf(acc[2]); pk.w = f2bf(acc[3]);
                    *(ushort4*)&vT_lds[(wave * 16 + ln16) * LDP + tm * 16 + quad * 4] = pk;
                } else {
                    r_reg[tm] = acc;
                }
            }
        }
        __syncthreads();

        // ---- phase2: scores = q @ k^T, softmax over q (columns), write att ----
        {
            float sc[4][4];  // [tm][r]; wave owns score columns f_k = wave*16+ln16
            for (int tm = 0; tm < 4; tm++) {
                f32x4 acc = {0.f, 0.f, 0.f, 0.f};
                for (int ks = 0; ks < 2; ks++) {
                    bf16x8 af = *(const bf16x8*)&q_lds[(tm * 16 + ln16) * LDP + ks * 32 + quad * 8];
                    bf16x8 bb = *(const bf16x8*)&k_lds[(wave * 16 + ln16) * LDP + ks * 32 + quad * 8];
                    acc = __builtin_amdgcn_mfma_f32_16x16x32_bf16(af, bb, acc, 0, 0, 0);
                }
                for (int r = 0; r < 4; r++) sc[tm][r] = acc[r];
            }
            // column reduction: lane holds 16 rows; quads (xor 16,32) complete it
            float mx = sc[0][0];
            for (int tm = 0; tm < 4; tm++)
                for (int r = 0; r < 4; r++) mx = fmaxf(mx, sc[tm][r]);
            mx = fmaxf(mx, __shfl_xor(mx, 16));
            mx = fmaxf(mx, __shfl_xor(mx, 32));
            float sum = 0.f;
            for (int tm = 0; tm < 4; tm++)
                for (int r = 0; r < 4; r++) {
                    sc[tm][r] = __expf(sc[tm][r] - mx);
                    sum += sc[tm][r];
                }
            sum += __shfl_xor(sum, 16);
            sum += __shfl_xor(sum, 32);
            float inv = 1.f / sum;
            for (int tm = 0; tm < 4; tm++)
                for (int r = 0; r < 4; r++)
                    att_lds[(tm * 16 + quad * 4 + r) * LDP + wave * 16 + ln16] =
                        f2bf(sc[tm][r] * inv);
        }
        __syncthreads();

        // ---- phase3: av = att @ v, + r (regs), relu, dot out_w ----
        {
            const float* ow = out_w + h * 64 + wave * 16;
            for (int tm = 0; tm < 4; tm++) {
                f32x4 acc = {0.f, 0.f, 0.f, 0.f};
                for (int ks = 0; ks < 2; ks++) {
                    bf16x8 af = *(const bf16x8*)&att_lds[(tm * 16 + ln16) * LDP + ks * 32 + quad * 8];
                    bf16x8 bb = *(const bf16x8*)&vT_lds[(wave * 16 + ln16) * LDP + ks * 32 + quad * 8];
                    acc = __builtin_amdgcn_mfma_f32_16x16x32_bf16(af, bb, acc, 0, 0, 0);
                }
                for (int r = 0; r < 4; r++) {
                    int f = tm * 16 + quad * 4 + r;
                    float mval = acc[r] + r_reg[tm][r];
                    if (mval > 0.f) {
                        acc_out += mval * ow[(size_t)f * 512 + ln16];
                    }
                }
            }
        }
        __syncthreads();
    }

    // ---- block reduction + sigmoid ----
    for (int off = 32; off >= 1; off >>= 1) acc_out += __shfl_xor(acc_out, off);
    if (lane == 0) red[wave] = acc_out;
    __syncthreads();
    if (tid == 0) {
        float s  = red[0] + red[1] + red[2] + red[3] + out_b[0];
        y[b] = 1.f / (1.f + __expf(-s));
    }
}

// Fallback (no usable workspace): per-head strided W gather, fp32 -> bf16.
__global__ __launch_bounds__(256) void autoint_kernel_nows(
        const int* __restrict__ fidx,
        const float* __restrict__ emb,
        const float* __restrict__ W0, const float* __restrict__ W1,
        const float* __restrict__ W2, const float* __restrict__ W3,
        const float* __restrict__ out_w, const float* __restrict__ out_b,
        float* __restrict__ y) {
    __shared__ __align__(16) unsigned short escratch[64 * 128];
    __shared__ __align__(16) unsigned short q_lds[64 * LDP];
    __shared__ __align__(16) unsigned short k_lds[64 * LDP];
    __shared__ __align__(16) unsigned short vT_lds[64 * LDP];
    __shared__ float red[4];

    const int b    = blockIdx.x;
    const int tid  = threadIdx.x;
    const int wave = tid >> 6;
    const int lane = tid & 63;
    const int quad = lane >> 4;
    const int ln16 = lane & 15;
    const int* idx = fidx + b * 64;

    for (int it = 0; it < 4; it++) {
        int s  = tid + it * 256;
        int tm = s >> 8, ks = (s >> 6) & 3, qd = (s >> 4) & 3, m = s & 15;
        int f  = tm * 16 + m;
        const float* src = emb + (size_t)idx[f] * 128 + ks * 32 + qd * 8;
        float4 lo = *(const float4*)src;
        float4 hi = *(const float4*)(src + 4);
        ushort4 pa, pb;
        pa.x = f2bf(lo.x); pa.y = f2bf(lo.y); pa.z = f2bf(lo.z); pa.w = f2bf(lo.w);
        pb.x = f2bf(hi.x); pb.y = f2bf(hi.y); pb.z = f2bf(hi.z); pb.w = f2bf(hi.w);
        *(ushort4*)&escratch[s * 8]     = pa;
        *(ushort4*)&escratch[s * 8 + 4] = pb;
    }
    __syncthreads();

    bf16x8 a[4][4];
    for (int tm = 0; tm < 4; tm++)
        for (int ks = 0; ks < 4; ks++)
            a[tm][ks] = *(const bf16x8*)&escratch[((tm * 4 + ks) * 64 + lane) * 8];
    unsigned short* att_lds = escratch;

    float acc_out = 0.f;
    f32x4 r_reg[4];

    for (int h = 0; h < 8; h++) {
        for (int m = 0; m < 4; m++) {
            const float* Wsel = (m == 0) ? W0 : (m == 1) ? W1 : (m == 2) ? W2 : W3;
            bf16x8 bf[4];
            for (int ks = 0; ks < 4; ks++) {
                union { unsigned short u[8]; bf16x8 v; } p;
                const float* base = Wsel + (size_t)(ks * 32 + quad * 8) * 512
                                    + h * 64 + wave * 16 + ln16;
                for (int j = 0; j < 8; j++) p.u[j] = f2bf(base[(size_t)j * 512]);
                bf[ks] = p.v;
            }
            for (int tm = 0; tm < 4; tm++) {
                f32x4 acc = {0.f, 0.f, 0.f, 0.f};
                for (int ks = 0; ks < 4; ks++)
                    acc = __builtin_amdgcn_mfma_f32_16x16x32_bf16(a[tm][ks], bf[ks], acc, 0, 0, 0);
                if (m == 0) {
                    for (int r = 0; r < 4; r++)
                        q_lds[(tm * 16 + quad * 4 + r) * LDP + wave * 16 + ln16] = f2bf(acc[r]);
                } else if (m == 1) {
                    for (int r = 0; r < 4; r++)
                        k_lds[(tm * 16 + quad * 4 + r) * LDP + wave * 16 + ln16] = f2bf(acc[r]);
                } else if (m == 2) {
                    ushort4 pk;
                    pk.x = f2bf(acc[0]); pk.y = f2bf(acc[1]);
                    pk.z = f2bf(acc[2]); pk.w = f2bf(acc[3]);
                    *(ushort4*)&vT_lds[(wave * 16 + ln16) * LDP + tm * 16 + quad * 4] = pk;
                } else {
                    r_reg[tm] = acc;
                }
            }
        }
        __syncthreads();
        {
            float sc[4][4];
            for (int tm = 0; tm < 4; tm++) {
                f32x4 acc = {0.f, 0.f, 0.f, 0.f};
                for (int ks = 0; ks < 2; ks++) {
                    bf16x8 af = *(const bf16x8*)&q_lds[(tm * 16 + ln16) * LDP + ks * 32 + quad * 8];
                    bf16x8 bb = *(const bf16x8*)&k_lds[(wave * 16 + ln16) * LDP + ks * 32 + quad * 8];
                    acc = __builtin_amdgcn_mfma_f32_16x16x32_bf16(af, bb, acc, 0, 0, 0);
                }
                for (int r = 0; r < 4; r++) sc[tm][r] = acc[r];
            }
            float mx = sc[0][0];
            for (int tm = 0; tm < 4; tm++)
                for (int r = 0; r < 4; r++) mx = fmaxf(mx, sc[tm][r]);
            mx = fmaxf(mx, __shfl_xor(mx, 16));
            mx = fmaxf(mx, __shfl_xor(mx, 32));
            float sum = 0.f;
            for (int tm = 0; tm < 4; tm++)
                for (int r = 0; r < 4; r++) {
                    sc[tm][r] = __expf(sc[tm][r] - mx);
                    sum += sc[tm][r];
                }
            sum += __shfl_xor(sum, 16);
            sum += __shfl_xor(sum, 32);
            float inv = 1.f / sum;
            for (int tm = 0; tm < 4; tm++)
                for (int r = 0; r < 4; r++)
                    att_lds[(tm * 16 + quad * 4 + r) * LDP + wave * 16 + ln16] =
                        f2bf(sc[tm][r] * inv);
        }
        __syncthreads();
        {
            const float* ow = out_w + h * 64 + wave * 16;
            for (int tm = 0; tm < 4; tm++) {
                f32x4 acc = {0.f, 0.f, 0.f, 0.f};
                for (int ks = 0; ks < 2; ks++) {
                    bf16x8 af = *(const bf16x8*)&att_lds[(tm * 16 + ln16) * LDP + ks * 32 + quad * 8];
                    bf16x8 bb = *(const bf16x8*)&vT_lds[(wave * 16 + ln16) * LDP + ks * 32 + quad * 8];
                    acc = __builtin_amdgcn_mfma_f32_16x16x32_bf16(af, bb, acc, 0, 0, 0);
                }
                for (int r = 0; r < 4; r++) {
                    int f = tm * 16 + quad * 4 + r;
                    float mval = acc[r] + r_reg[tm][r];
                    if (mval > 0.f) acc_out += mval * ow[(size_t)f * 512 + ln16];
                }
            }
        }
        __syncthreads();
    }
    for (int off = 32; off >= 1; off >>= 1) acc_out += __shfl_xor(acc_out, off);
    if (lane == 0) red[wave] = acc_out;
    __syncthreads();
    if (tid == 0) {
        float s = red[0] + red[1] + red[2] + red[3] + out_b[0];
        y[b] = 1.f / (1.f + __expf(-s));
    }
}

extern "C" void kernel_launch(void* const* d_in, const int* in_sizes, int n_in,
                              void* d_out, int out_size, void* d_ws, size_t ws_size,
                              hipStream_t stream) {
    (void)in_sizes; (void)n_in; (void)out_size;
    const int*   fidx = (const int*)d_in[0];
    const float* emb  = (const float*)d_in[1];
    const float* Wq   = (const float*)d_in[2];
    const float* Wk   = (const float*)d_in[3];
    const float* Wv   = (const float*)d_in[4];
    const float* Wr   = (const float*)d_in[5];
    const float* ow   = (const float*)d_in[6];
    const float* ob   = (const float*)d_in[7];
    float*       yy   = (float*)d_out;

    const size_t wt_bytes = (size_t)4 * 512 * 128 * sizeof(unsigned short);  // 512 KB
    if (d_ws != nullptr && ws_size >= wt_bytes) {
        unsigned short* Wt = (unsigned short*)d_ws;
        prep_w<<<256, 256, 0, stream>>>(Wq, Wk, Wv, Wr, Wt);
        autoint_kernel<<<2048, 256, 0, stream>>>(fidx, emb, Wt, ow, ob, yy);
    } else {
        autoint_kernel_nows<<<2048, 256, 0, stream>>>(fidx, emb, Wq, Wk, Wv, Wr, ow, ob, yy);
    }
}